// Round 1
// 309.764 us; speedup vs baseline: 1.0483x; 1.0483x over previous
//
#include <hip/hip_runtime.h>
#include <math.h>

// (B, T, D, H, L) = (8, 512, 128, 128, 2). All fp32 I/O.
#define BB 8
#define TT 512
#define DD 128
#define HH 128
#define BT_ (BB * TT)                 // 4096
static const size_t BTH = (size_t)BT_ * HH;  // 524288

// ws layout: act planes [0,6*BTH) : q | k | ifpack(2*BTH) | vopack(2*BTH)
//   q:      act + 0      [row][h]
//   k:      act + BTH    [row][h]     (pre-scaled by 1/sqrt(H) in proj)
//   ifpack: act + 2*BTH  [row][2h+{0:i,1:f}]
//   vopack: act + 4*BTH  [row][2h+{0:v,1:o}]  (o gets *= invden in denom_kernel)
// hbuf = act + 6*BTH (layer-1 output, planar [row][h]).
//   hbuf doubles as nbuf (old-n history) between proj and scan2 of each layer:
//   layer 1: nscan writes nbuf into hbuf region, denom consumes it, then scan2
//            overwrites the region with layer-1 h (stream-ordered, safe).
//   layer 2: hbuf (layer-2 input) is dead after proj, so nscan reuses it again.
// Wt (12 x 128 x 128 transposed weights) lives in d_out's first 196608
// floats; consumed by both proj dispatches, then fully overwritten by the
// final scan2 (stream-ordered, so this is safe).

struct WArgs { const float* W[6]; };
struct BArgs { const float* b[6]; };

template <int CTRL>
__device__ __forceinline__ float dpp_add(float x) {
  int y = __builtin_amdgcn_update_dpp(0, __builtin_bit_cast(int, x), CTRL,
                                      0xF, 0xF, true);
  return x + __builtin_bit_cast(float, y);
}

__device__ __forceinline__ float rd_lane(float x, int l) {
  return __builtin_bit_cast(
      float, __builtin_amdgcn_readlane(__builtin_bit_cast(int, x), l));
}

// ---------------------------------------------------------------------------
// Transpose all 12 weight slabs: Wt[l*6+p][d][h] = W_p[l][h][d].
// grid (16, 12): 4x4 tiles of 32x32 per slab. block 256.
// ---------------------------------------------------------------------------
__global__ __launch_bounds__(256)
void transpose_w(WArgs w, float* __restrict__ Wt) {
  __shared__ float t[32][33];
  const int l = blockIdx.y / 6, p = blockIdx.y % 6;
  const float* src = w.W[p] + (size_t)l * HH * DD;
  float* dst = Wt + (size_t)blockIdx.y * HH * DD;
  const int ty0 = (blockIdx.x >> 2) * 32, tx0 = (blockIdx.x & 3) * 32;
  const int tx = threadIdx.x & 31, ty = threadIdx.x >> 5;
#pragma unroll
  for (int j = 0; j < 32; j += 8)
    t[ty + j][tx] = src[(size_t)(ty0 + ty + j) * DD + tx0 + tx];
  __syncthreads();
#pragma unroll
  for (int j = 0; j < 32; j += 8)
    dst[(size_t)(tx0 + ty + j) * HH + ty0 + tx] = t[tx][ty + j];
}

// ---------------------------------------------------------------------------
// Projection: out[p][row][h] = act_p( sum_d X[row][d] * Wt_p[d][h] + b_p[h] )
// Rank-1-update GEMM, coalesced Wt rows. grid (BT_/32, 6), block 256.
// Thread = 2 rows x 8 h. LDS X tile padded to 132 (bank-conflict-free).
// ---------------------------------------------------------------------------
__global__ __launch_bounds__(256)
void proj_kernel(const float* __restrict__ X, const float* __restrict__ Wtl,
                 BArgs args, float* __restrict__ act) {
  __shared__ float xs[32][132];
  const int p = blockIdx.y;
  const int row0 = blockIdx.x * 32;
  const int tid = threadIdx.x;
  {
    const float4* xg = (const float4*)(X + (size_t)row0 * DD);
#pragma unroll
    for (int i = 0; i < 4; ++i) {
      int u = tid + 256 * i;  // float4 index within 32x128 tile
      float4 v = xg[u];
      *(float4*)&xs[u >> 5][(u & 31) * 4] = v;
    }
  }
  __syncthreads();

  const int h0 = (tid & 15) * 8;
  const int r0 = (tid >> 4) * 2;
  const float* wtp = Wtl + (size_t)p * HH * DD;

  float acc[2][8];
#pragma unroll
  for (int r = 0; r < 2; ++r)
#pragma unroll
    for (int j = 0; j < 8; ++j) acc[r][j] = 0.f;

  for (int d0 = 0; d0 < DD; d0 += 4) {
    float4 wa[4], wb[4];
#pragma unroll
    for (int i = 0; i < 4; ++i) {
      wa[i] = *(const float4*)(wtp + (size_t)(d0 + i) * HH + h0);
      wb[i] = *(const float4*)(wtp + (size_t)(d0 + i) * HH + h0 + 4);
    }
    float4 x0 = *(const float4*)&xs[r0][d0];
    float4 x1 = *(const float4*)&xs[r0 + 1][d0];
    const float xa[4] = {x0.x, x0.y, x0.z, x0.w};
    const float xb[4] = {x1.x, x1.y, x1.z, x1.w};
#pragma unroll
    for (int i = 0; i < 4; ++i) {
      acc[0][0] = fmaf(xa[i], wa[i].x, acc[0][0]);
      acc[0][1] = fmaf(xa[i], wa[i].y, acc[0][1]);
      acc[0][2] = fmaf(xa[i], wa[i].z, acc[0][2]);
      acc[0][3] = fmaf(xa[i], wa[i].w, acc[0][3]);
      acc[0][4] = fmaf(xa[i], wb[i].x, acc[0][4]);
      acc[0][5] = fmaf(xa[i], wb[i].y, acc[0][5]);
      acc[0][6] = fmaf(xa[i], wb[i].z, acc[0][6]);
      acc[0][7] = fmaf(xa[i], wb[i].w, acc[0][7]);
      acc[1][0] = fmaf(xb[i], wa[i].x, acc[1][0]);
      acc[1][1] = fmaf(xb[i], wa[i].y, acc[1][1]);
      acc[1][2] = fmaf(xb[i], wa[i].z, acc[1][2]);
      acc[1][3] = fmaf(xb[i], wa[i].w, acc[1][3]);
      acc[1][4] = fmaf(xb[i], wb[i].x, acc[1][4]);
      acc[1][5] = fmaf(xb[i], wb[i].y, acc[1][5]);
      acc[1][6] = fmaf(xb[i], wb[i].z, acc[1][6]);
      acc[1][7] = fmaf(xb[i], wb[i].w, acc[1][7]);
    }
  }

  const float4 b0 = *(const float4*)(args.b[p] + h0);
  const float4 b1 = *(const float4*)(args.b[p] + h0 + 4);
  const float bias[8] = {b0.x, b0.y, b0.z, b0.w, b1.x, b1.y, b1.z, b1.w};
#pragma unroll
  for (int r = 0; r < 2; ++r) {
    const size_t row = (size_t)row0 + r0 + r;
    float v[8];
#pragma unroll
    for (int j = 0; j < 8; ++j) {
      float a = acc[r][j] + bias[j];
      if (p == 1)      a *= 0.088388347648318447f;   // 1/sqrt(128)
      else if (p == 3) a = __expf(a);
      else if (p >= 4) a = 1.0f / (1.0f + __expf(-a));
      v[j] = a;
    }
    if (p == 0) {
      float* dst = act + row * HH + h0;
      *(float4*)dst = make_float4(v[0], v[1], v[2], v[3]);
      *(float4*)(dst + 4) = make_float4(v[4], v[5], v[6], v[7]);
    } else if (p == 1) {
      float* dst = act + BTH + row * HH + h0;
      *(float4*)dst = make_float4(v[0], v[1], v[2], v[3]);
      *(float4*)(dst + 4) = make_float4(v[4], v[5], v[6], v[7]);
    } else if (p == 3 || p == 4) {       // i -> slot 0, f -> slot 1
      float* dst = act + 2 * BTH + row * 2 * HH + 2 * h0 + (p == 3 ? 0 : 1);
#pragma unroll
      for (int j = 0; j < 8; ++j) dst[2 * j] = v[j];
    } else {                             // v -> slot 0, o -> slot 1
      float* dst = act + 4 * BTH + row * 2 * HH + 2 * h0 + (p == 2 ? 0 : 1);
#pragma unroll
      for (int j = 0; j < 8; ++j) dst[2 * j] = v[j];
    }
  }
}

// ---------------------------------------------------------------------------
// nscan: the n recurrence is independent of C — hoist it. 1024 independent
// scalar chains (b,p), each stores the OLD n (n_{t-1}) per step:
//   nbuf[b][t][p] = n_{t-1}[p];  n = f_t*n + i_t*k_t.
// grid 16 x 64 (one lane per chain); coalesced across p.
// ---------------------------------------------------------------------------
__global__ __launch_bounds__(64)
void nscan_kernel(const float* __restrict__ act, float* __restrict__ nbuf) {
  const int lane = threadIdx.x;
  const int cid = blockIdx.x * 64 + lane;
  const int b = cid >> 7, p = cid & 127;
  const size_t boff = (size_t)b * TT * HH;
  const float* kp = act + BTH + boff + p;
  const float* ifp = act + 2 * BTH + 2 * boff + 2 * p;
  float* np = nbuf + boff + p;
  float n = 0.f;
#pragma unroll 8
  for (int t = 0; t < TT; ++t) {
    const float2 iff = *(const float2*)(ifp + (size_t)t * 2 * HH);  // (i,f)
    const float kv = kp[(size_t)t * HH];
    np[(size_t)t * HH] = n;              // OLD n, per reference semantics
    n = fmaf(iff.y, n, iff.x * kv);
  }
}

// ---------------------------------------------------------------------------
// denom: invden_t = 1/max(|dot(n_{t-1}, q_t)|, 1), folded into the o gate
// in place: vopack o-slot *= invden. grid 1024 (b*128 + t/4), block 256
// (wave per t). Removes the whole denominator path from the hot scan.
// ---------------------------------------------------------------------------
__global__ __launch_bounds__(256)
void denom_kernel(float* __restrict__ act, const float* __restrict__ nbuf) {
  const int tid = threadIdx.x;
  const int lane = tid & 63, wid = tid >> 6;
  const int b = blockIdx.x >> 7;
  const int t = (blockIdx.x & 127) * 4 + wid;
  const size_t row = (size_t)b * TT + t;
  const float2 nv = *(const float2*)(nbuf + row * HH + 2 * lane);
  const float2 qv = *(const float2*)(act + row * HH + 2 * lane);
  float dp = fmaf(nv.x, qv.x, nv.y * qv.y);
  dp = dpp_add<0x111>(dp);  // row_shr:1
  dp = dpp_add<0x112>(dp);  // row_shr:2
  dp = dpp_add<0x114>(dp);  // row_shr:4
  dp = dpp_add<0x118>(dp);  // row_shr:8
  dp = dpp_add<0x142>(dp);  // row_bcast:15
  dp = dpp_add<0x143>(dp);  // row_bcast:31
  const float dpv = rd_lane(dp, 63);
  const float inv = __builtin_amdgcn_rcpf(fmaxf(fabsf(dpv), 1.0f));
  float* vo = act + 4 * BTH + row * 2 * HH;
  vo[4 * lane + 1] *= inv;              // o at [2h+1], h = 2*lane
  vo[4 * lane + 3] *= inv;              // h = 2*lane+1
}

// ---------------------------------------------------------------------------
// scan2: C recurrence + h output. 4x finer partition than before:
// grid 256 (b = blk&7 XCD co-location, rg = blk>>3), block 256 = 4 waves.
// Wave wid owns row p = rg*4+wid of C (per batch); lane owns cols 2l,2l+1.
// -> 1024 waves (1/SIMD on all 256 CUs) vs 256 before.
// Per 8-step group: q/k tiles LDS-staged (shared by 4 waves, prefetched one
// group ahead); gates preloaded per-lane (lane>>3 = within-group t) and
// broadcast per step via v_readlane; per-step serial chain = 1 FMA (C).
// h-tilde partials deferred: per-wave LDS transpose (padded rows) + local
// 8-sum + 3-level DPP; lane 8j+7 holds sum for t0+j and already has that
// t's o' (= o*invden) in its preloaded gate reg. h staged in hlds, stored
// as float4 rows by wave 0 one group later.
// ---------------------------------------------------------------------------
__global__ __launch_bounds__(256)
void scan2_kernel(const float* __restrict__ act, float* __restrict__ hout) {
  __shared__ __align__(16) float qlds[2][8][128];
  __shared__ __align__(16) float klds[2][8][128];
  __shared__ __align__(16) float red[4][8][66];   // 66: pad -> <=2-way banks
  __shared__ __align__(16) float hlds[2][8][4];
  const int tid = threadIdx.x;
  const int lane = tid & 63, wid = tid >> 6;
  const int b = blockIdx.x & 7, rg = blockIdx.x >> 3;
  const int p = rg * 4 + wid;
  const size_t boff = (size_t)b * TT * HH;
  const float* qp = act + boff;
  const float* kp = act + BTH + boff;
  const float* ifp = act + 2 * BTH + 2 * boff + 2 * p;
  const float* vop = act + 4 * BTH + 2 * boff + 2 * p;

  const int st_t = tid >> 5, st_c = (tid & 31) * 4;  // staging: 1 float4/thread
  const int j2 = 2 * lane;
  const int tsub = lane >> 3;                        // within-group t preloaded

  float C0 = 0.f, C1 = 0.f;
  float4 rq, rk;
  float2 gif, gvo, nif, nvo;

  // prologue: stage group 0 + its gates
  rq = *(const float4*)(qp + (size_t)st_t * HH + st_c);
  rk = *(const float4*)(kp + (size_t)st_t * HH + st_c);
  *(float4*)&qlds[0][st_t][st_c] = rq;
  *(float4*)&klds[0][st_t][st_c] = rk;
  gif = *(const float2*)(ifp + (size_t)tsub * 2 * HH);   // (i,f) at t=tsub
  gvo = *(const float2*)(vop + (size_t)tsub * 2 * HH);   // (v,o') at t=tsub
  __syncthreads();

#pragma unroll 2
  for (int g = 0; g < 64; ++g) {
    const int buf = g & 1;
    const int tn = (g + 1 < 64) ? (g + 1) * 8 : 63 * 8;  // clamp tail (dead)
    // 1) prefetch next group's tiles + gates (consumed ~1 group later)
    rq = *(const float4*)(qp + (size_t)(tn + st_t) * HH + st_c);
    rk = *(const float4*)(kp + (size_t)(tn + st_t) * HH + st_c);
    nif = *(const float2*)(ifp + (size_t)(tn + tsub) * 2 * HH);
    nvo = *(const float2*)(vop + (size_t)(tn + tsub) * 2 * HH);
    // 2) drain previous group's h (hlds[buf^1], visible since last barrier)
    if (g > 0 && wid == 0 && lane < 8) {
      const float4 hv = *(const float4*)&hlds[buf ^ 1][lane][0];
      *(float4*)(hout + ((size_t)b * TT + (size_t)(g - 1) * 8 + lane) * HH +
                 rg * 4) = hv;
    }
    // 3) fragments for this group
    float2 qv[8], kv[8];
#pragma unroll
    for (int j = 0; j < 8; ++j) {
      qv[j] = *(const float2*)&qlds[buf][j][j2];
      kv[j] = *(const float2*)&klds[buf][j][j2];
    }
    // 4) 8 steps; h-partial uses OLD C; serial chain = 1 FMA/step per C elem
    const float ar = gif.x * gvo.x;      // i*v at t = g*8+tsub (this lane)
    float pj[8];
#pragma unroll
    for (int j = 0; j < 8; ++j) {
      const float sf = rd_lane(gif.y, 8 * j);
      const float sa = rd_lane(ar, 8 * j);
      pj[j] = fmaf(C0, qv[j].x, C1 * qv[j].y);
      C0 = fmaf(sf, C0, sa * kv[j].x);
      C1 = fmaf(sf, C1, sa * kv[j].y);
    }
    // 5) deferred reduce: per-wave LDS transpose + local sum + 3-level DPP
#pragma unroll
    for (int j = 0; j < 8; ++j) red[wid][j][lane] = pj[j];
    asm volatile("s_waitcnt lgkmcnt(0)" ::: "memory");  // rule-18 pattern:
    __builtin_amdgcn_sched_barrier(0);                  // no reorder past wait
    {
      const int rj = lane >> 3, rr = lane & 7;
      const float2 a0 = *(const float2*)&red[wid][rj][rr * 8];
      const float2 a1 = *(const float2*)&red[wid][rj][rr * 8 + 2];
      const float2 a2 = *(const float2*)&red[wid][rj][rr * 8 + 4];
      const float2 a3 = *(const float2*)&red[wid][rj][rr * 8 + 6];
      float s = ((a0.x + a0.y) + (a1.x + a1.y)) +
                ((a2.x + a2.y) + (a3.x + a3.y));
      s = dpp_add<0x111>(s);
      s = dpp_add<0x112>(s);
      s = dpp_add<0x114>(s);             // lane 8j+7 = full sum for t0+j
      const float hval = s * gvo.y;      // gvo.y = o*invden at t0+tsub (==j)
      if ((lane & 7) == 7) hlds[buf][tsub][wid] = hval;
    }
    // 6) write next group's tiles into the other buffer; rotate gates
    *(float4*)&qlds[buf ^ 1][st_t][st_c] = rq;
    *(float4*)&klds[buf ^ 1][st_t][st_c] = rk;
    gif = nif; gvo = nvo;
    __syncthreads();
  }
  // tail: group 63's h
  if (wid == 0 && lane < 8) {
    const float4 hv = *(const float4*)&hlds[1][lane][0];
    *(float4*)(hout + ((size_t)b * TT + 504 + lane) * HH + rg * 4) = hv;
  }
}

// ---------------------------------------------------------------------------
extern "C" void kernel_launch(void* const* d_in, const int* in_sizes, int n_in,
                              void* d_out, int out_size, void* d_ws,
                              size_t ws_size, hipStream_t stream) {
  (void)in_sizes; (void)n_in; (void)out_size; (void)ws_size;
  const float* x = (const float*)d_in[0];
  float* act = (float*)d_ws;            // 6 * BTH floats
  float* hbuf = act + 6 * BTH;          // BTH floats; doubles as nbuf
  float* Wt = (float*)d_out;            // 12*128*128 floats, overwritten later

  WArgs wa;
  for (int j = 0; j < 6; ++j) wa.W[j] = (const float*)d_in[1 + j];
  transpose_w<<<dim3(16, 12), 256, 0, stream>>>(wa, Wt);

  for (int l = 0; l < 2; ++l) {
    BArgs ba;
    for (int j = 0; j < 6; ++j)
      ba.b[j] = (const float*)d_in[7 + j] + (size_t)l * HH;
    const float* wtl = Wt + (size_t)l * 6 * HH * DD;
    const float* xin = (l == 0) ? x : hbuf;
    float* hdst = (l == 0) ? hbuf : (float*)d_out;
    proj_kernel<<<dim3(BT_ / 32, 6), 256, 0, stream>>>(xin, wtl, ba, act);
    // n/denominator path is independent of C: precompute and fold into o.
    nscan_kernel<<<16, 64, 0, stream>>>(act, hbuf);       // nbuf := hbuf region
    denom_kernel<<<1024, 256, 0, stream>>>(act, hbuf);
    scan2_kernel<<<256, 256, 0, stream>>>(act, hdst);
  }
}

// Round 2
// 259.845 us; speedup vs baseline: 1.2497x; 1.1921x over previous
//
#include <hip/hip_runtime.h>
#include <math.h>

// (B, T, D, H, L) = (8, 512, 128, 128, 2). All fp32 I/O.
#define BB 8
#define TT 512
#define DD 128
#define HH 128
#define BT_ (BB * TT)                 // 4096
static const size_t BTH = (size_t)BT_ * HH;  // 524288

// ws layout: act planes [0,6*BTH) : q | k | ifpack(2*BTH) | vopack(2*BTH)
//   q:      act + 0      [row][h]
//   k:      act + BTH    [row][h]     (pre-scaled by 1/sqrt(H) in proj)
//   ifpack: act + 2*BTH  [row][2h+{0:i,1:f}]
//   vopack: act + 4*BTH  [row][2h+{0:v,1:o}]  (o *= invden in denom_kernel)
// hbuf = act + 6*BTH (layer-1 output, planar [row][h]); doubles as nbuf
// (old-n history) between the n-scan and scan2 of each layer.
// d_out scratch map (floats):
//   [0,        196608)  Wt   (12 x 128 x 128 transposed weights)
//   [196608,   327680)  segAB[b][p][seg]{A,B}   (8*128*64*2)
//   [327680,   393216)  nstart[b][p][seg]       (8*128*64)
// All consumed before the final scan2 overwrites d_out (stream-ordered).

struct WArgs { const float* W[6]; };
struct BArgs { const float* b[6]; };

template <int CTRL>
__device__ __forceinline__ float dpp_add(float x) {
  int y = __builtin_amdgcn_update_dpp(0, __builtin_bit_cast(int, x), CTRL,
                                      0xF, 0xF, true);
  return x + __builtin_bit_cast(float, y);
}

// DPP move with identity fill: invalid lanes keep `old` (bound_ctrl=false).
template <int CTRL>
__device__ __forceinline__ float dpp_mov(float old, float x) {
  int y = __builtin_amdgcn_update_dpp(__builtin_bit_cast(int, old),
                                      __builtin_bit_cast(int, x), CTRL,
                                      0xF, 0xF, false);
  return __builtin_bit_cast(float, y);
}

__device__ __forceinline__ float rd_lane(float x, int l) {
  return __builtin_bit_cast(
      float, __builtin_amdgcn_readlane(__builtin_bit_cast(int, x), l));
}

// ---------------------------------------------------------------------------
// Transpose all 12 weight slabs: Wt[l*6+p][d][h] = W_p[l][h][d].
// ---------------------------------------------------------------------------
__global__ __launch_bounds__(256)
void transpose_w(WArgs w, float* __restrict__ Wt) {
  __shared__ float t[32][33];
  const int l = blockIdx.y / 6, p = blockIdx.y % 6;
  const float* src = w.W[p] + (size_t)l * HH * DD;
  float* dst = Wt + (size_t)blockIdx.y * HH * DD;
  const int ty0 = (blockIdx.x >> 2) * 32, tx0 = (blockIdx.x & 3) * 32;
  const int tx = threadIdx.x & 31, ty = threadIdx.x >> 5;
#pragma unroll
  for (int j = 0; j < 32; j += 8)
    t[ty + j][tx] = src[(size_t)(ty0 + ty + j) * DD + tx0 + tx];
  __syncthreads();
#pragma unroll
  for (int j = 0; j < 32; j += 8)
    dst[(size_t)(tx0 + ty + j) * HH + ty0 + tx] = t[tx][ty + j];
}

// ---------------------------------------------------------------------------
// Projection: out[p][row][h] = act_p( sum_d X[row][d] * Wt_p[d][h] + b_p[h] )
// grid (BT_/32, 6), block 256. Thread = 2 rows x 8 h.
// ---------------------------------------------------------------------------
__global__ __launch_bounds__(256)
void proj_kernel(const float* __restrict__ X, const float* __restrict__ Wtl,
                 BArgs args, float* __restrict__ act) {
  __shared__ float xs[32][132];
  const int p = blockIdx.y;
  const int row0 = blockIdx.x * 32;
  const int tid = threadIdx.x;
  {
    const float4* xg = (const float4*)(X + (size_t)row0 * DD);
#pragma unroll
    for (int i = 0; i < 4; ++i) {
      int u = tid + 256 * i;
      float4 v = xg[u];
      *(float4*)&xs[u >> 5][(u & 31) * 4] = v;
    }
  }
  __syncthreads();

  const int h0 = (tid & 15) * 8;
  const int r0 = (tid >> 4) * 2;
  const float* wtp = Wtl + (size_t)p * HH * DD;

  float acc[2][8];
#pragma unroll
  for (int r = 0; r < 2; ++r)
#pragma unroll
    for (int j = 0; j < 8; ++j) acc[r][j] = 0.f;

  for (int d0 = 0; d0 < DD; d0 += 4) {
    float4 wa[4], wb[4];
#pragma unroll
    for (int i = 0; i < 4; ++i) {
      wa[i] = *(const float4*)(wtp + (size_t)(d0 + i) * HH + h0);
      wb[i] = *(const float4*)(wtp + (size_t)(d0 + i) * HH + h0 + 4);
    }
    float4 x0 = *(const float4*)&xs[r0][d0];
    float4 x1 = *(const float4*)&xs[r0 + 1][d0];
    const float xa[4] = {x0.x, x0.y, x0.z, x0.w};
    const float xb[4] = {x1.x, x1.y, x1.z, x1.w};
#pragma unroll
    for (int i = 0; i < 4; ++i) {
      acc[0][0] = fmaf(xa[i], wa[i].x, acc[0][0]);
      acc[0][1] = fmaf(xa[i], wa[i].y, acc[0][1]);
      acc[0][2] = fmaf(xa[i], wa[i].z, acc[0][2]);
      acc[0][3] = fmaf(xa[i], wa[i].w, acc[0][3]);
      acc[0][4] = fmaf(xa[i], wb[i].x, acc[0][4]);
      acc[0][5] = fmaf(xa[i], wb[i].y, acc[0][5]);
      acc[0][6] = fmaf(xa[i], wb[i].z, acc[0][6]);
      acc[0][7] = fmaf(xa[i], wb[i].w, acc[0][7]);
      acc[1][0] = fmaf(xb[i], wa[i].x, acc[1][0]);
      acc[1][1] = fmaf(xb[i], wa[i].y, acc[1][1]);
      acc[1][2] = fmaf(xb[i], wa[i].z, acc[1][2]);
      acc[1][3] = fmaf(xb[i], wa[i].w, acc[1][3]);
      acc[1][4] = fmaf(xb[i], wb[i].x, acc[1][4]);
      acc[1][5] = fmaf(xb[i], wb[i].y, acc[1][5]);
      acc[1][6] = fmaf(xb[i], wb[i].z, acc[1][6]);
      acc[1][7] = fmaf(xb[i], wb[i].w, acc[1][7]);
    }
  }

  const float4 b0 = *(const float4*)(args.b[p] + h0);
  const float4 b1 = *(const float4*)(args.b[p] + h0 + 4);
  const float bias[8] = {b0.x, b0.y, b0.z, b0.w, b1.x, b1.y, b1.z, b1.w};
#pragma unroll
  for (int r = 0; r < 2; ++r) {
    const size_t row = (size_t)row0 + r0 + r;
    float v[8];
#pragma unroll
    for (int j = 0; j < 8; ++j) {
      float a = acc[r][j] + bias[j];
      if (p == 1)      a *= 0.088388347648318447f;   // 1/sqrt(128)
      else if (p == 3) a = __expf(a);
      else if (p >= 4) a = 1.0f / (1.0f + __expf(-a));
      v[j] = a;
    }
    if (p == 0) {
      float* dst = act + row * HH + h0;
      *(float4*)dst = make_float4(v[0], v[1], v[2], v[3]);
      *(float4*)(dst + 4) = make_float4(v[4], v[5], v[6], v[7]);
    } else if (p == 1) {
      float* dst = act + BTH + row * HH + h0;
      *(float4*)dst = make_float4(v[0], v[1], v[2], v[3]);
      *(float4*)(dst + 4) = make_float4(v[4], v[5], v[6], v[7]);
    } else if (p == 3 || p == 4) {       // i -> slot 0, f -> slot 1
      float* dst = act + 2 * BTH + row * 2 * HH + 2 * h0 + (p == 3 ? 0 : 1);
#pragma unroll
      for (int j = 0; j < 8; ++j) dst[2 * j] = v[j];
    } else {                             // v -> slot 0, o -> slot 1
      float* dst = act + 4 * BTH + row * 2 * HH + 2 * h0 + (p == 2 ? 0 : 1);
#pragma unroll
      for (int j = 0; j < 8; ++j) dst[2 * j] = v[j];
    }
  }
}

// ---------------------------------------------------------------------------
// n-recurrence (independent of C), 3-phase parallel scan over T.
// n_t = f_t * n_{t-1} + i_t * k_t per chain (b,p); nbuf stores OLD n.
// ---------------------------------------------------------------------------
// Phase 1: per-segment (8 steps) affine summary A=prod f, B s.t. n_out=A n+B.
// grid 512 (b = blk&7, seg = blk>>3), block 128 (p). Coalesced.
__global__ __launch_bounds__(128)
void nseg_kernel(const float* __restrict__ act, float* __restrict__ segAB) {
  const int b = blockIdx.x & 7, seg = blockIdx.x >> 3;
  const int p = threadIdx.x;
  const size_t boff = (size_t)b * TT * HH;
  const float* kp = act + BTH + boff + p;
  const float* ifp = act + 2 * BTH + 2 * boff + 2 * p;
  const int t0 = seg * 8;
  float A = 1.f, Bv = 0.f;
#pragma unroll
  for (int j = 0; j < 8; ++j) {
    const float2 iff = *(const float2*)(ifp + (size_t)(t0 + j) * 2 * HH);
    const float kv = kp[(size_t)(t0 + j) * HH];
    A *= iff.y;
    Bv = fmaf(iff.y, Bv, iff.x * kv);
  }
  *(float2*)(segAB + ((size_t)(b * 128 + p) * 64 + seg) * 2) =
      make_float2(A, Bv);
}

// Phase 2: per-chain inclusive pair-scan of 64 segment summaries (one wave
// per chain, lane = seg). Canonical wave64 scan: shr1,2,4,8 + bcast15,31,
// identity-preserving composition. Stores exclusive-prefix B = n at seg start.
__global__ __launch_bounds__(64)
void nsum_kernel(const float* __restrict__ segAB, float* __restrict__ nstart) {
  const int chain = blockIdx.x;       // b*128+p
  const int lane = threadIdx.x;
  const float2 ab = *(const float2*)(segAB + ((size_t)chain * 64 + lane) * 2);
  float A = ab.x, Bv = ab.y;
  // compose T_l = T_l ∘ T_{l-s}: B = A*B_s + B; A = A*A_s
#define SCAN_LVL(CTRL)                          \
  {                                             \
    float As = dpp_mov<CTRL>(1.0f, A);          \
    float Bs = dpp_mov<CTRL>(0.0f, Bv);         \
    Bv = fmaf(A, Bs, Bv);                       \
    A = A * As;                                 \
  }
  SCAN_LVL(0x111)  // row_shr:1
  SCAN_LVL(0x112)  // row_shr:2
  SCAN_LVL(0x114)  // row_shr:4
  SCAN_LVL(0x118)  // row_shr:8
  SCAN_LVL(0x142)  // row_bcast:15
  SCAN_LVL(0x143)  // row_bcast:31
#undef SCAN_LVL
  // n starts at 0, so n at start of seg s = inclusive-B of seg s-1; seg 0 = 0.
  const int idx = (lane + 1) & 63;
  nstart[(size_t)chain * 64 + idx] = (lane == 63) ? 0.f : Bv;
}

// Phase 3: expand — redo the 8 local steps from the segment-start n, storing
// OLD n (reference semantics). grid 512 (b,seg), block 128 (p). Coalesced.
__global__ __launch_bounds__(128)
void nexp_kernel(const float* __restrict__ act,
                 const float* __restrict__ nstart, float* __restrict__ nbuf) {
  const int b = blockIdx.x & 7, seg = blockIdx.x >> 3;
  const int p = threadIdx.x;
  const size_t boff = (size_t)b * TT * HH;
  const float* kp = act + BTH + boff + p;
  const float* ifp = act + 2 * BTH + 2 * boff + 2 * p;
  float* np = nbuf + boff + p;
  const int t0 = seg * 8;
  float n = nstart[(size_t)(b * 128 + p) * 64 + seg];
#pragma unroll
  for (int j = 0; j < 8; ++j) {
    const float2 iff = *(const float2*)(ifp + (size_t)(t0 + j) * 2 * HH);
    const float kv = kp[(size_t)(t0 + j) * HH];
    np[(size_t)(t0 + j) * HH] = n;
    n = fmaf(iff.y, n, iff.x * kv);
  }
}

// ---------------------------------------------------------------------------
// denom: invden_t = 1/max(|dot(n_{t-1}, q_t)|, 1), folded into o in place.
// ---------------------------------------------------------------------------
__global__ __launch_bounds__(256)
void denom_kernel(float* __restrict__ act, const float* __restrict__ nbuf) {
  const int tid = threadIdx.x;
  const int lane = tid & 63, wid = tid >> 6;
  const int b = blockIdx.x >> 7;
  const int t = (blockIdx.x & 127) * 4 + wid;
  const size_t row = (size_t)b * TT + t;
  const float2 nv = *(const float2*)(nbuf + row * HH + 2 * lane);
  const float2 qv = *(const float2*)(act + row * HH + 2 * lane);
  float dp = fmaf(nv.x, qv.x, nv.y * qv.y);
  dp = dpp_add<0x111>(dp);
  dp = dpp_add<0x112>(dp);
  dp = dpp_add<0x114>(dp);
  dp = dpp_add<0x118>(dp);
  dp = dpp_add<0x142>(dp);
  dp = dpp_add<0x143>(dp);
  const float dpv = rd_lane(dp, 63);
  const float inv = __builtin_amdgcn_rcpf(fmaxf(fabsf(dpv), 1.0f));
  float* vo = act + 4 * BTH + row * 2 * HH;
  vo[4 * lane + 1] *= inv;
  vo[4 * lane + 3] *= inv;
}

// ---------------------------------------------------------------------------
// scan2 v2: barrier-free, 1 wave per block, 1024 blocks (b = blk&7, p=blk>>3).
// Lane owns C cols 2l,2l+1. Per 8-step group: q/k float2 per lane loaded
// DIRECTLY from global (coalesced, prefetched one group ahead in regs);
// gates preloaded per-lane (tsub=lane>>3) and broadcast via readlane.
// h-tilde reduce: per-wave-private LDS transpose, software-pipelined one
// group behind (ds_reads of group g-1 issue before group g's FMA block).
// No __syncthreads anywhere. h stored directly (8 masked lanes per group).
// ---------------------------------------------------------------------------
struct GBuf {
  float2 q[8], k[8];
  float2 gif, gvo;   // (i,f) and (v,o') at t = t0 + (lane>>3)
};

__global__ __launch_bounds__(64)
void scan2_kernel(const float* __restrict__ act, float* __restrict__ hout) {
  __shared__ __align__(16) float red[2][8][68];
  const int lane = threadIdx.x;
  const int b = blockIdx.x & 7;
  const int p = blockIdx.x >> 3;
  const size_t boff = (size_t)b * TT * HH;
  const float* qp = act + boff + 2 * lane;
  const float* kp = act + BTH + boff + 2 * lane;
  const float* ifp = act + 2 * BTH + 2 * boff + 2 * p;
  const float* vop = act + 4 * BTH + 2 * boff + 2 * p;
  const int tsub = lane >> 3;
  const int rj = lane >> 3, rr = lane & 7;
  float* hbase = hout + (size_t)b * TT * HH + p;

  float C0 = 0.f, C1 = 0.f;

  auto load_group = [&](int t0, GBuf& g) {
#pragma unroll
    for (int j = 0; j < 8; ++j) {
      g.q[j] = *(const float2*)(qp + (size_t)(t0 + j) * HH);
      g.k[j] = *(const float2*)(kp + (size_t)(t0 + j) * HH);
    }
    g.gif = *(const float2*)(ifp + (size_t)(t0 + tsub) * 2 * HH);
    g.gvo = *(const float2*)(vop + (size_t)(t0 + tsub) * 2 * HH);
  };

  auto compute_steps = [&](const GBuf& g, int buf) {
    const float ar = g.gif.x * g.gvo.x;   // i*v at t0+tsub
    float pj[8];
#pragma unroll
    for (int j = 0; j < 8; ++j) {
      const float sf = rd_lane(g.gif.y, 8 * j);
      const float sa = rd_lane(ar, 8 * j);
      pj[j] = fmaf(C0, g.q[j].x, C1 * g.q[j].y);   // OLD C
      C0 = fmaf(sf, C0, sa * g.k[j].x);
      C1 = fmaf(sf, C1, sa * g.k[j].y);
    }
#pragma unroll
    for (int j = 0; j < 8; ++j) red[buf][j][lane] = pj[j];
  };

  auto reduce_group = [&](int buf, int t0, float oh) {
    const float4 a = *(const float4*)&red[buf][rj][rr * 8];
    const float4 c = *(const float4*)&red[buf][rj][rr * 8 + 4];
    float s = ((a.x + a.y) + (a.z + a.w)) + ((c.x + c.y) + (c.z + c.w));
    s = dpp_add<0x111>(s);
    s = dpp_add<0x112>(s);
    s = dpp_add<0x114>(s);               // lane 8*rj+7 = full sum for t0+rj
    if (rr == 7) hbase[(size_t)(t0 + rj) * HH] = s * oh;
  };

  GBuf A, B;
  load_group(0, A);
  load_group(8, B);
  compute_steps(A, 0);
  float oh0 = A.gvo.y, oh1;

#pragma unroll 1
  for (int gg = 0; gg < 31; ++gg) {
    const int g1 = 2 * gg + 1;           // current group = B
    load_group(8 * (g1 + 1), A);         // prefetch (A's oh already saved)
    compute_steps(B, 1);
    oh1 = B.gvo.y;
    reduce_group(0, 8 * (g1 - 1), oh0);  // finish group g1-1
    const int g2 = 2 * gg + 2;           // current group = A
    load_group(8 * (g2 + 1), B);
    compute_steps(A, 0);
    oh0 = A.gvo.y;
    reduce_group(1, 8 * (g2 - 1), oh1);  // finish group g2-1
  }
  // g=63 (current = B), pending reduce of g=62 (buf 0, oh0)
  compute_steps(B, 1);
  oh1 = B.gvo.y;
  reduce_group(0, 8 * 62, oh0);
  reduce_group(1, 8 * 63, oh1);
}

// ---------------------------------------------------------------------------
extern "C" void kernel_launch(void* const* d_in, const int* in_sizes, int n_in,
                              void* d_out, int out_size, void* d_ws,
                              size_t ws_size, hipStream_t stream) {
  (void)in_sizes; (void)n_in; (void)out_size; (void)ws_size;
  const float* x = (const float*)d_in[0];
  float* act = (float*)d_ws;            // 6 * BTH floats
  float* hbuf = act + 6 * BTH;          // BTH floats; doubles as nbuf
  float* Wt = (float*)d_out;            // [0, 196608)
  float* segAB = Wt + 196608;           // [196608, 327680)
  float* nstart = Wt + 327680;          // [327680, 393216)

  WArgs wa;
  for (int j = 0; j < 6; ++j) wa.W[j] = (const float*)d_in[1 + j];
  transpose_w<<<dim3(16, 12), 256, 0, stream>>>(wa, Wt);

  for (int l = 0; l < 2; ++l) {
    BArgs ba;
    for (int j = 0; j < 6; ++j)
      ba.b[j] = (const float*)d_in[7 + j] + (size_t)l * HH;
    const float* wtl = Wt + (size_t)l * 6 * HH * DD;
    const float* xin = (l == 0) ? x : hbuf;
    float* hdst = (l == 0) ? hbuf : (float*)d_out;
    proj_kernel<<<dim3(BT_ / 32, 6), 256, 0, stream>>>(xin, wtl, ba, act);
    // n/denominator path (independent of C): 3-phase parallel scan, then
    // fold 1/denom into the o gate.
    nseg_kernel<<<512, 128, 0, stream>>>(act, segAB);
    nsum_kernel<<<1024, 64, 0, stream>>>(segAB, nstart);
    nexp_kernel<<<512, 128, 0, stream>>>(act, nstart, hbuf);
    denom_kernel<<<1024, 256, 0, stream>>>(act, hbuf);
    scan2_kernel<<<1024, 64, 0, stream>>>(act, hdst);
  }
}

// Round 4
// 258.101 us; speedup vs baseline: 1.2581x; 1.0068x over previous
//
#include <hip/hip_runtime.h>
#include <math.h>

// (B, T, D, H, L) = (8, 512, 128, 128, 2). All fp32 I/O.
#define BB 8
#define TT 512
#define DD 128
#define HH 128
#define BT_ (BB * TT)                 // 4096
static const size_t BTH = (size_t)BT_ * HH;  // 524288

// ws layout: act planes [0,6*BTH) : q | k | ifpack(2*BTH) | vopack(2*BTH)
//   q:      act + 0      [row][h]
//   k:      act + BTH    [row][h]     (pre-scaled by 1/sqrt(H) in proj)
//   ifpack: act + 2*BTH  [row][2h+{0:i,1:f}]
//   vopack: act + 4*BTH  [row][2h+{0:v,1:o}]  (o *= invden in nexp_denom)
// hbuf = act + 6*BTH (layer-1 output, planar [row][h]).
// d_out scratch map (floats):
//   [0,        196608)  Wt   (12 x 128 x 128 transposed weights)
//   [196608,   327680)  segAB[b][p][seg]{A,B}   (8*128*64*2)
//   [327680,   393216)  nstart[b][p][seg]       (8*128*64)
// All consumed before the final scan2 overwrites d_out (stream-ordered).

struct WArgs { const float* W[6]; };
struct BArgs { const float* b[6]; };

template <int CTRL>
__device__ __forceinline__ float dpp_add(float x) {
  int y = __builtin_amdgcn_update_dpp(0, __builtin_bit_cast(int, x), CTRL,
                                      0xF, 0xF, true);
  return x + __builtin_bit_cast(float, y);
}

// DPP move with identity fill: invalid lanes keep `old` (bound_ctrl=false).
template <int CTRL>
__device__ __forceinline__ float dpp_mov(float old, float x) {
  int y = __builtin_amdgcn_update_dpp(__builtin_bit_cast(int, old),
                                      __builtin_bit_cast(int, x), CTRL,
                                      0xF, 0xF, false);
  return __builtin_bit_cast(float, y);
}

__device__ __forceinline__ float rd_lane(float x, int l) {
  return __builtin_bit_cast(
      float, __builtin_amdgcn_readlane(__builtin_bit_cast(int, x), l));
}

// ---------------------------------------------------------------------------
// Transpose all 12 weight slabs: Wt[l*6+p][d][h] = W_p[l][h][d].
// ---------------------------------------------------------------------------
__global__ __launch_bounds__(256)
void transpose_w(WArgs w, float* __restrict__ Wt) {
  __shared__ float t[32][33];
  const int l = blockIdx.y / 6, p = blockIdx.y % 6;
  const float* src = w.W[p] + (size_t)l * HH * DD;
  float* dst = Wt + (size_t)blockIdx.y * HH * DD;
  const int ty0 = (blockIdx.x >> 2) * 32, tx0 = (blockIdx.x & 3) * 32;
  const int tx = threadIdx.x & 31, ty = threadIdx.x >> 5;
#pragma unroll
  for (int j = 0; j < 32; j += 8)
    t[ty + j][tx] = src[(size_t)(ty0 + ty + j) * DD + tx0 + tx];
  __syncthreads();
#pragma unroll
  for (int j = 0; j < 32; j += 8)
    dst[(size_t)(tx0 + ty + j) * HH + ty0 + tx] = t[tx][ty + j];
}

// ---------------------------------------------------------------------------
// Projection: out[p][row][h] = act_p( sum_d X[row][d] * Wt_p[d][h] + b_p[h] )
// grid (BT_/32, 6), block 256. Thread = 2 rows x 8 h.
// ---------------------------------------------------------------------------
__global__ __launch_bounds__(256)
void proj_kernel(const float* __restrict__ X, const float* __restrict__ Wtl,
                 BArgs args, float* __restrict__ act) {
  __shared__ float xs[32][132];
  const int p = blockIdx.y;
  const int row0 = blockIdx.x * 32;
  const int tid = threadIdx.x;
  {
    const float4* xg = (const float4*)(X + (size_t)row0 * DD);
#pragma unroll
    for (int i = 0; i < 4; ++i) {
      int u = tid + 256 * i;
      float4 v = xg[u];
      *(float4*)&xs[u >> 5][(u & 31) * 4] = v;
    }
  }
  __syncthreads();

  const int h0 = (tid & 15) * 8;
  const int r0 = (tid >> 4) * 2;
  const float* wtp = Wtl + (size_t)p * HH * DD;

  float acc[2][8];
#pragma unroll
  for (int r = 0; r < 2; ++r)
#pragma unroll
    for (int j = 0; j < 8; ++j) acc[r][j] = 0.f;

  for (int d0 = 0; d0 < DD; d0 += 4) {
    float4 wa[4], wb[4];
#pragma unroll
    for (int i = 0; i < 4; ++i) {
      wa[i] = *(const float4*)(wtp + (size_t)(d0 + i) * HH + h0);
      wb[i] = *(const float4*)(wtp + (size_t)(d0 + i) * HH + h0 + 4);
    }
    float4 x0 = *(const float4*)&xs[r0][d0];
    float4 x1 = *(const float4*)&xs[r0 + 1][d0];
    const float xa[4] = {x0.x, x0.y, x0.z, x0.w};
    const float xb[4] = {x1.x, x1.y, x1.z, x1.w};
#pragma unroll
    for (int i = 0; i < 4; ++i) {
      acc[0][0] = fmaf(xa[i], wa[i].x, acc[0][0]);
      acc[0][1] = fmaf(xa[i], wa[i].y, acc[0][1]);
      acc[0][2] = fmaf(xa[i], wa[i].z, acc[0][2]);
      acc[0][3] = fmaf(xa[i], wa[i].w, acc[0][3]);
      acc[0][4] = fmaf(xa[i], wb[i].x, acc[0][4]);
      acc[0][5] = fmaf(xa[i], wb[i].y, acc[0][5]);
      acc[0][6] = fmaf(xa[i], wb[i].z, acc[0][6]);
      acc[0][7] = fmaf(xa[i], wb[i].w, acc[0][7]);
      acc[1][0] = fmaf(xb[i], wa[i].x, acc[1][0]);
      acc[1][1] = fmaf(xb[i], wa[i].y, acc[1][1]);
      acc[1][2] = fmaf(xb[i], wa[i].z, acc[1][2]);
      acc[1][3] = fmaf(xb[i], wa[i].w, acc[1][3]);
      acc[1][4] = fmaf(xb[i], wb[i].x, acc[1][4]);
      acc[1][5] = fmaf(xb[i], wb[i].y, acc[1][5]);
      acc[1][6] = fmaf(xb[i], wb[i].z, acc[1][6]);
      acc[1][7] = fmaf(xb[i], wb[i].w, acc[1][7]);
    }
  }

  const float4 b0 = *(const float4*)(args.b[p] + h0);
  const float4 b1 = *(const float4*)(args.b[p] + h0 + 4);
  const float bias[8] = {b0.x, b0.y, b0.z, b0.w, b1.x, b1.y, b1.z, b1.w};
#pragma unroll
  for (int r = 0; r < 2; ++r) {
    const size_t row = (size_t)row0 + r0 + r;
    float v[8];
#pragma unroll
    for (int j = 0; j < 8; ++j) {
      float a = acc[r][j] + bias[j];
      if (p == 1)      a *= 0.088388347648318447f;   // 1/sqrt(128)
      else if (p == 3) a = __expf(a);
      else if (p >= 4) a = 1.0f / (1.0f + __expf(-a));
      v[j] = a;
    }
    if (p == 0) {
      float* dst = act + row * HH + h0;
      *(float4*)dst = make_float4(v[0], v[1], v[2], v[3]);
      *(float4*)(dst + 4) = make_float4(v[4], v[5], v[6], v[7]);
    } else if (p == 1) {
      float* dst = act + BTH + row * HH + h0;
      *(float4*)dst = make_float4(v[0], v[1], v[2], v[3]);
      *(float4*)(dst + 4) = make_float4(v[4], v[5], v[6], v[7]);
    } else if (p == 3 || p == 4) {       // i -> slot 0, f -> slot 1
      float* dst = act + 2 * BTH + row * 2 * HH + 2 * h0 + (p == 3 ? 0 : 1);
#pragma unroll
      for (int j = 0; j < 8; ++j) dst[2 * j] = v[j];
    } else {                             // v -> slot 0, o -> slot 1
      float* dst = act + 4 * BTH + row * 2 * HH + 2 * h0 + (p == 2 ? 0 : 1);
#pragma unroll
      for (int j = 0; j < 8; ++j) dst[2 * j] = v[j];
    }
  }
}

// ---------------------------------------------------------------------------
// n-recurrence (independent of C), parallel scan over T.
// n_t = f_t * n_{t-1} + i_t * k_t per chain (b,p).
// ---------------------------------------------------------------------------
// Phase 1: per-segment (8 steps) affine summary A=prod f, B s.t. n_out=A n+B.
__global__ __launch_bounds__(128)
void nseg_kernel(const float* __restrict__ act, float* __restrict__ segAB) {
  const int b = blockIdx.x & 7, seg = blockIdx.x >> 3;
  const int p = threadIdx.x;
  const size_t boff = (size_t)b * TT * HH;
  const float* kp = act + BTH + boff + p;
  const float* ifp = act + 2 * BTH + 2 * boff + 2 * p;
  const int t0 = seg * 8;
  float A = 1.f, Bv = 0.f;
#pragma unroll
  for (int j = 0; j < 8; ++j) {
    const float2 iff = *(const float2*)(ifp + (size_t)(t0 + j) * 2 * HH);
    const float kv = kp[(size_t)(t0 + j) * HH];
    A *= iff.y;
    Bv = fmaf(iff.y, Bv, iff.x * kv);
  }
  *(float2*)(segAB + ((size_t)(b * 128 + p) * 64 + seg) * 2) =
      make_float2(A, Bv);
}

// Phase 2: per-chain inclusive pair-scan of 64 segment summaries; stores
// exclusive-prefix B = n at segment start (n starts at 0).
__global__ __launch_bounds__(64)
void nsum_kernel(const float* __restrict__ segAB, float* __restrict__ nstart) {
  const int chain = blockIdx.x;       // b*128+p
  const int lane = threadIdx.x;
  const float2 ab = *(const float2*)(segAB + ((size_t)chain * 64 + lane) * 2);
  float A = ab.x, Bv = ab.y;
#define SCAN_LVL(CTRL)                          \
  {                                             \
    float As = dpp_mov<CTRL>(1.0f, A);          \
    float Bs = dpp_mov<CTRL>(0.0f, Bv);         \
    Bv = fmaf(A, Bs, Bv);                       \
    A = A * As;                                 \
  }
  SCAN_LVL(0x111)
  SCAN_LVL(0x112)
  SCAN_LVL(0x114)
  SCAN_LVL(0x118)
  SCAN_LVL(0x142)
  SCAN_LVL(0x143)
#undef SCAN_LVL
  const int idx = (lane + 1) & 63;
  nstart[(size_t)chain * 64 + idx] = (lane == 63) ? 0.f : Bv;
}

// Phase 3 + denom fused: re-run the 8 local n-steps from the segment-start n
// (never materializing n_old to global), block-reduce dot(n_{t-1}, q_t) over
// the 128 p's, and scale the o-slot of vopack in place by 1/max(|den|,1).
// grid 512 (b = blk&7, seg = blk>>3), block 128 (p). Coalesced.
__global__ __launch_bounds__(128)
void nexp_denom_kernel(float* __restrict__ act,
                       const float* __restrict__ nstart) {
  __shared__ float pl[8][132];
  __shared__ float den[8];
  const int b = blockIdx.x & 7, seg = blockIdx.x >> 3;
  const int p = threadIdx.x;
  const size_t boff = (size_t)b * TT * HH;
  const float* qp = act + boff + p;
  const float* kp = act + BTH + boff + p;
  const float* ifp = act + 2 * BTH + 2 * boff + 2 * p;
  const int t0 = seg * 8;
  float n = nstart[(size_t)(b * 128 + p) * 64 + seg];
  float prod[8];
#pragma unroll
  for (int j = 0; j < 8; ++j) {
    const float2 iff = *(const float2*)(ifp + (size_t)(t0 + j) * 2 * HH);
    const float kv = kp[(size_t)(t0 + j) * HH];
    const float qv = qp[(size_t)(t0 + j) * HH];
    prod[j] = n * qv;                  // n_{t-1}[p] * q_t[p]
    n = fmaf(iff.y, n, iff.x * kv);
  }
#pragma unroll
  for (int j = 0; j < 8; ++j) pl[j][p] = prod[j];
  __syncthreads();
  {
    const int j = p >> 4, c = p & 15;  // 16 threads per t
    const float4 a = *(const float4*)&pl[j][c * 8];
    const float4 d = *(const float4*)&pl[j][c * 8 + 4];
    float s = ((a.x + a.y) + (a.z + a.w)) + ((d.x + d.y) + (d.z + d.w));
    s = dpp_add<0x111>(s);
    s = dpp_add<0x112>(s);
    s = dpp_add<0x114>(s);
    s = dpp_add<0x118>(s);             // lane 15 of each 16-row = full sum
    if ((p & 15) == 15)
      den[j] = __builtin_amdgcn_rcpf(fmaxf(fabsf(s), 1.0f));
  }
  __syncthreads();
  float* vop = act + 4 * BTH + 2 * boff;
#pragma unroll
  for (int j = 0; j < 8; ++j)
    vop[(size_t)(t0 + j) * 2 * HH + 2 * p + 1] *= den[j];
}

// ---------------------------------------------------------------------------
// scan2 v4: barrier-free, 1 wave per block, 2 C-rows per wave.
// 512 blocks (b = blk&7 XCD co-location, pb = blk>>3 -> rows 2pb, 2pb+1).
// q/k loads (float2 per lane per t) are SHARED by both rows -> L2 read
// amplification halves vs 1-row waves; per-group compute doubles, so the
// one-group-ahead prefetch covers L2 latency (~600 cyc issue distance).
// Per 8-step group: gates preloaded per-lane (tsub=lane>>3), broadcast via
// readlane; per-step serial chain = 1 FMA per C element. h-tilde reduce:
// per-wave LDS transpose pipelined one group behind (validated in v2/v3).
// ---------------------------------------------------------------------------
struct GB {
  float2 q[8], k[8];
  float2 gf0, gf1;   // (i,f) rows 0/1 at t = t0 + (lane>>3)
  float2 gv0, gv1;   // (v,o') rows 0/1 at t = t0 + (lane>>3)
};

__global__ __launch_bounds__(64)
void scan2_kernel(const float* __restrict__ act, float* __restrict__ hout) {
  __shared__ __align__(16) float red[2][2][8][68];  // [row][par][j][lane]
  const int lane = threadIdx.x;
  const int b = blockIdx.x & 7;
  const int pb = blockIdx.x >> 3;
  const int p0 = 2 * pb, p1 = 2 * pb + 1;
  const size_t boff = (size_t)b * TT * HH;
  const float* qp = act + boff + 2 * lane;
  const float* kp = act + BTH + boff + 2 * lane;
  const float* if0 = act + 2 * BTH + 2 * boff + 2 * p0;
  const float* if1 = act + 2 * BTH + 2 * boff + 2 * p1;
  const float* vo0 = act + 4 * BTH + 2 * boff + 2 * p0;
  const float* vo1 = act + 4 * BTH + 2 * boff + 2 * p1;
  const int tsub = lane >> 3;
  const int rj = lane >> 3, rr = lane & 7;
  float* hb0 = hout + (size_t)b * TT * HH + p0;
  float* hb1 = hout + (size_t)b * TT * HH + p1;

  float C00 = 0.f, C01 = 0.f, C10 = 0.f, C11 = 0.f;

  auto load_group = [&](int t0, GB& g) {
#pragma unroll
    for (int j = 0; j < 8; ++j) {
      g.q[j] = *(const float2*)(qp + (size_t)(t0 + j) * HH);
      g.k[j] = *(const float2*)(kp + (size_t)(t0 + j) * HH);
    }
    const size_t go = (size_t)(t0 + tsub) * 2 * HH;
    g.gf0 = *(const float2*)(if0 + go);
    g.gf1 = *(const float2*)(if1 + go);
    g.gv0 = *(const float2*)(vo0 + go);
    g.gv1 = *(const float2*)(vo1 + go);
  };

  auto compute_steps = [&](const GB& g, int par) {
    const float ar0 = g.gf0.x * g.gv0.x;   // i*v row0 at t0+tsub
    const float ar1 = g.gf1.x * g.gv1.x;
    float pj0[8], pj1[8];
#pragma unroll
    for (int j = 0; j < 8; ++j) {
      const float sf0 = rd_lane(g.gf0.y, 8 * j);
      const float sa0 = rd_lane(ar0, 8 * j);
      const float sf1 = rd_lane(g.gf1.y, 8 * j);
      const float sa1 = rd_lane(ar1, 8 * j);
      pj0[j] = fmaf(C00, g.q[j].x, C01 * g.q[j].y);  // OLD C
      pj1[j] = fmaf(C10, g.q[j].x, C11 * g.q[j].y);
      C00 = fmaf(sf0, C00, sa0 * g.k[j].x);
      C01 = fmaf(sf0, C01, sa0 * g.k[j].y);
      C10 = fmaf(sf1, C10, sa1 * g.k[j].x);
      C11 = fmaf(sf1, C11, sa1 * g.k[j].y);
    }
#pragma unroll
    for (int j = 0; j < 8; ++j) red[0][par][j][lane] = pj0[j];
#pragma unroll
    for (int j = 0; j < 8; ++j) red[1][par][j][lane] = pj1[j];
  };

  // oh0/oh1 are full per-lane register copies of gvo.y; lane 8*rj+7 holds
  // o'(t0+rj), exactly what the store needs after the DPP reduce.
  auto reduce_group = [&](int par, int t0, float oh0, float oh1) {
    const float4 a0 = *(const float4*)&red[0][par][rj][rr * 8];
    const float4 a1 = *(const float4*)&red[0][par][rj][rr * 8 + 4];
    const float4 b0 = *(const float4*)&red[1][par][rj][rr * 8];
    const float4 b1 = *(const float4*)&red[1][par][rj][rr * 8 + 4];
    float s0 = ((a0.x + a0.y) + (a0.z + a0.w)) + ((a1.x + a1.y) + (a1.z + a1.w));
    float s1 = ((b0.x + b0.y) + (b0.z + b0.w)) + ((b1.x + b1.y) + (b1.z + b1.w));
    s0 = dpp_add<0x111>(s0);
    s1 = dpp_add<0x111>(s1);
    s0 = dpp_add<0x112>(s0);
    s1 = dpp_add<0x112>(s1);
    s0 = dpp_add<0x114>(s0);
    s1 = dpp_add<0x114>(s1);           // lane 8*rj+7 = full sum for t0+rj
    if (rr == 7) {
      hb0[(size_t)(t0 + rj) * HH] = s0 * oh0;
      hb1[(size_t)(t0 + rj) * HH] = s1 * oh1;
    }
  };

  GB A, B;
  load_group(0, A);
  load_group(8, B);
  compute_steps(A, 0);
  float om0 = A.gv0.y, om1 = A.gv1.y;  // oh of group 0 (pending reduce)
  load_group(16, A);

#pragma unroll 1
  for (int gg = 0; gg < 31; ++gg) {
    const int g1 = 2 * gg + 1;
    compute_steps(B, 1);
    const float o10 = B.gv0.y, o11 = B.gv1.y;
    load_group(8 * (g1 + 2 < 64 ? g1 + 2 : 63), B);
    reduce_group(0, 8 * (g1 - 1), om0, om1);
    om0 = o10; om1 = o11;
    const int g2 = g1 + 1;
    compute_steps(A, 0);
    const float o20 = A.gv0.y, o21 = A.gv1.y;
    load_group(8 * (g2 + 2 < 64 ? g2 + 2 : 63), A);
    reduce_group(1, 8 * (g2 - 1), om0, om1);
    om0 = o20; om1 = o21;
  }
  // computed 0..62, reduced 0..61; B holds group 63
  compute_steps(B, 1);
  reduce_group(0, 8 * 62, om0, om1);
  reduce_group(1, 8 * 63, B.gv0.y, B.gv1.y);
}

// ---------------------------------------------------------------------------
extern "C" void kernel_launch(void* const* d_in, const int* in_sizes, int n_in,
                              void* d_out, int out_size, void* d_ws,
                              size_t ws_size, hipStream_t stream) {
  (void)in_sizes; (void)n_in; (void)out_size; (void)ws_size;
  const float* x = (const float*)d_in[0];
  float* act = (float*)d_ws;            // 6 * BTH floats
  float* hbuf = act + 6 * BTH;          // BTH floats (layer-1 h)
  float* Wt = (float*)d_out;            // [0, 196608)
  float* segAB = Wt + 196608;           // [196608, 327680)
  float* nstart = Wt + 327680;          // [327680, 393216)

  WArgs wa;
  for (int j = 0; j < 6; ++j) wa.W[j] = (const float*)d_in[1 + j];
  transpose_w<<<dim3(16, 12), 256, 0, stream>>>(wa, Wt);

  for (int l = 0; l < 2; ++l) {
    BArgs ba;
    for (int j = 0; j < 6; ++j)
      ba.b[j] = (const float*)d_in[7 + j] + (size_t)l * HH;
    const float* wtl = Wt + (size_t)l * 6 * HH * DD;
    const float* xin = (l == 0) ? x : hbuf;
    float* hdst = (l == 0) ? hbuf : (float*)d_out;
    proj_kernel<<<dim3(BT_ / 32, 6), 256, 0, stream>>>(xin, wtl, ba, act);
    // n/denominator path (independent of C): segment summaries, chain scan,
    // then fused expand+denominator folding 1/den into the o gate.
    nseg_kernel<<<512, 128, 0, stream>>>(act, segAB);
    nsum_kernel<<<1024, 64, 0, stream>>>(segAB, nstart);
    nexp_denom_kernel<<<512, 128, 0, stream>>>(act, nstart);
    scan2_kernel<<<512, 64, 0, stream>>>(act, hdst);
  }
}